// Round 8
// baseline (243.051 us; speedup 1.0000x reference)
//
#include <hip/hip_runtime.h>
#include <hip/hip_bf16.h>
#include <stdint.h>

// Problem constants
#define NB 4
#define NT 2048
#define NC 1024
#define NH 16
#define NHD 64
#define NM (NB*NT)   // 8192 rows

typedef __attribute__((ext_vector_type(8))) __bf16 bf16x8;
typedef __attribute__((ext_vector_type(4))) float floatx4;
typedef __attribute__((ext_vector_type(8))) unsigned short ushortx8;

#define AS1(p) ((const __attribute__((address_space(1))) void*)(p))
#define AS3(p) ((__attribute__((address_space(3))) void*)(p))

__device__ __forceinline__ unsigned short f2bf(float f) {
    union { float f; unsigned int u; } v; v.f = f;
    unsigned int u = v.u;
    return (unsigned short)((u + 0x7FFFu + ((u >> 16) & 1u)) >> 16);
}
// pack two fp32 -> (bf16(hi)<<16)|bf16(lo), RTZ, single v_perm_b32
__device__ __forceinline__ unsigned int pk2(float lo, float hi) {
    union { float f; unsigned int u; } a, b; a.f = hi; b.f = lo;
    return __builtin_amdgcn_perm(a.u, b.u, 0x07060302u);
}

// ===== fragment-tiled layout (for all GEMM operands) =====
// matrix (rows x 1024 cols) stored as 16x32 tiles of 512 shorts:
//   tile (R=row/16, C=col/32) at offset (R*32 + C)*512
//   element (r=row&15, c=col&31) at ((c>>3)*16 + r)*8 + (c&7)

// ---------------- merged cast fp32 -> bf16, fragment-tiled ------------------
__global__ void cast_all(const float* __restrict__ x,
                         const float* __restrict__ w0, const float* __restrict__ w1,
                         const float* __restrict__ w2, const float* __restrict__ w3,
                         unsigned short* __restrict__ xo,
                         unsigned short* __restrict__ o0, unsigned short* __restrict__ o1,
                         unsigned short* __restrict__ o2, unsigned short* __restrict__ o3)
{
    const int wid  = (blockIdx.x * blockDim.x + threadIdx.x) >> 6;
    const int lane = threadIdx.x & 63;
    const float* in; unsigned short* out; int tile;
    if (wid < 16384) { in = x; out = xo; tile = wid; }
    else {
        const int t = wid - 16384;
        tile = t & 2047;
        switch (t >> 11) {
            case 0: in = w0; out = o0; break;
            case 1: in = w1; out = o1; break;
            case 2: in = w2; out = o2; break;
            default: in = w3; out = o3; break;
        }
    }
    const int R = tile >> 5, C = tile & 31;
    const float* src = in + ((size_t)(R*16 + (lane >> 2)))*1024 + C*32 + (lane & 3)*8;
    const floatx4 v0 = *(const floatx4*)src;
    const floatx4 v1 = *(const floatx4*)(src + 4);
    ushortx8 o;
    o[0] = f2bf(v0[0]); o[1] = f2bf(v0[1]); o[2] = f2bf(v0[2]); o[3] = f2bf(v0[3]);
    o[4] = f2bf(v1[0]); o[5] = f2bf(v1[1]); o[6] = f2bf(v1[2]); o[7] = f2bf(v1[3]);
    *(ushortx8*)&out[(size_t)tile*512 + (((lane & 3)*16 + (lane >> 2)))*8] = o;
}

// ---------------- GEMM core: Out = (A @ W^T + bias) * oscale ----------------
// A, W fragment-tiled, K=1024. BK=32, 128x128 tile, 4 waves, dbuf 32KB LDS,
// raw s_barrier + counted vmcnt(4) (R4 structure — best measured).
// LEDGER: prefetch depth 0 (R3) == 1 (R4) == 2 (R6 tri-buf, slightly worse)
// == 73.4-74.6us; QKV-merge (R5) regressed to 90us. The 128^2/K=1024
// structure is at its shape-local floor (~700 TF); GEMM experiments closed.
// MODE 0: Out fp32 row-major MxN (final projection)          [mfma(X, W)]
// MODE 1: Out bf16 Q/K fragment order, swapped operands      [mfma(W, X)]
// MODE 2: Out bf16 V^T key-permuted A-frag order             [mfma(X, W)]
#define TM 128
#define TN 128
#define BK 32

template<int MODE>
__device__ __forceinline__ void gemm_core(
    const unsigned short* __restrict__ A,
    const unsigned short* __restrict__ W,
    const float* __restrict__ bias,
    void* __restrict__ Out,
    unsigned short* As, unsigned short* Bs,   // each 2 x 4096 shorts (dbuf)
    int m_base, int n_base, float oscale)
{
    const int tid  = threadIdx.x;
    const int lane = tid & 63;
    const int wv   = tid >> 6;
    const int quad = lane >> 4;
    const int l16  = lane & 15;
    const int wm = (wv >> 1) * 64;
    const int wn = (wv & 1) * 64;

    floatx4 acc[4][4];
    #pragma unroll
    for (int i = 0; i < 4; ++i)
        #pragma unroll
        for (int j = 0; j < 4; ++j)
            acc[i][j] = (floatx4){0.f, 0.f, 0.f, 0.f};

    const int kct = NC >> 5;   // 32 k-tiles

    const unsigned short* At = A + ((size_t)((m_base >> 4) + wv*2) * kct) * 512 + (size_t)lane*8;
    const unsigned short* Wt = W + ((size_t)((n_base >> 4) + wv*2) * kct) * 512 + (size_t)lane*8;
    const size_t rstride = (size_t)kct * 512;

    // prologue: stage k-tile 0 into buf 0 (4 loads per wave)
    #pragma unroll
    for (int i = 0; i < 2; ++i) {
        __builtin_amdgcn_global_load_lds(AS1(At + i*rstride),
                                         AS3(&As[(wv*2 + i)*512]), 16, 0, 0);
        __builtin_amdgcn_global_load_lds(AS1(Wt + i*rstride),
                                         AS3(&Bs[(wv*2 + i)*512]), 16, 0, 0);
    }

    #pragma unroll 1
    for (int kt = 0; kt < 32; ++kt) {
        const int cur = (kt & 1) << 12;        // 0 / 4096 shorts
        const int nxt = 4096 - cur;
        if (kt < 31) {
            #pragma unroll
            for (int i = 0; i < 2; ++i) {
                __builtin_amdgcn_global_load_lds(
                    AS1(At + (size_t)(kt+1)*512 + i*rstride),
                    AS3(&As[nxt + (wv*2 + i)*512]), 16, 0, 0);
                __builtin_amdgcn_global_load_lds(
                    AS1(Wt + (size_t)(kt+1)*512 + i*rstride),
                    AS3(&Bs[nxt + (wv*2 + i)*512]), 16, 0, 0);
            }
            // own 4 newest (tile kt+1) stay in flight; tile kt's 4 are done
            asm volatile("s_waitcnt vmcnt(4)" ::: "memory");
        } else {
            asm volatile("s_waitcnt vmcnt(0)" ::: "memory");
        }
        __builtin_amdgcn_s_barrier();          // tile kt ready in buf cur

        bf16x8 af[4], bfr[4];
        #pragma unroll
        for (int mi = 0; mi < 4; ++mi)
            af[mi] = *(const bf16x8*)&As[cur + ((wv >> 1)*4 + mi)*512 + lane*8];
        #pragma unroll
        for (int ni = 0; ni < 4; ++ni)
            bfr[ni] = *(const bf16x8*)&Bs[cur + ((wv & 1)*4 + ni)*512 + lane*8];

        #pragma unroll
        for (int mi = 0; mi < 4; ++mi)
            #pragma unroll
            for (int ni = 0; ni < 4; ++ni) {
                if (MODE == 1)   // swapped: d on quad axis, t on l16
                    acc[mi][ni] = __builtin_amdgcn_mfma_f32_16x16x32_bf16(
                        bfr[ni], af[mi], acc[mi][ni], 0, 0, 0);
                else
                    acc[mi][ni] = __builtin_amdgcn_mfma_f32_16x16x32_bf16(
                        af[mi], bfr[ni], acc[mi][ni], 0, 0, 0);
            }
        __builtin_amdgcn_s_barrier();          // all waves done reading buf cur
    }

    // epilogue
    #pragma unroll
    for (int mi = 0; mi < 4; ++mi) {
        #pragma unroll
        for (int ni = 0; ni < 4; ++ni) {
            if (MODE == 0) {
                const int col = n_base + wn + ni*16 + l16;
                const float bv = bias[col & 1023];
                #pragma unroll
                for (int r = 0; r < 4; ++r) {
                    const int row = m_base + wm + mi*16 + quad*4 + r;
                    ((float*)Out)[(size_t)row * NC + col] =
                        (acc[mi][ni][r] + bv) * oscale;
                }
            } else if (MODE == 1) {
                const int d0 = n_base + wn + ni*16 + quad*4;
                const int t  = m_base + wm + mi*16 + l16;
                const float4 b4 = *(const float4*)&bias[d0];
                const int bb = t >> 11, tt = t & (NT - 1);
                const int h  = (d0 >> 6) & (NH - 1), dd0 = d0 & 63;
                const int bh = bb * NH + h;
                const size_t idx0 =
                    ((size_t)((bh*128 + (tt >> 4))*2 + (dd0 >> 5)))*512
                    + (size_t)((((dd0 >> 3) & 3)*16 + (tt & 15))*8 + (dd0 & 7));
                ushort4 st;
                st.x = f2bf((acc[mi][ni][0] + b4.x) * oscale);
                st.y = f2bf((acc[mi][ni][1] + b4.y) * oscale);
                st.z = f2bf((acc[mi][ni][2] + b4.z) * oscale);
                st.w = f2bf((acc[mi][ni][3] + b4.w) * oscale);
                *(ushort4*)&((unsigned short*)Out)[idx0] = st;
            } else {
                const int col = n_base + wn + ni*16 + l16;
                const float bv = bias[col & 1023];
                const int row0 = m_base + wm + mi*16 + quad*4;
                const int bb = row0 >> 11, t0 = row0 & (NT - 1);
                const int h  = (col >> 6) & (NH - 1), hd = col & 63;
                const int bh = bb * NH + h;
                const int tk0 = t0 & 31;
                const int qv  = (tk0 >> 2) & 3;
                const int jv0 = (tk0 >> 4) << 2;      // tk0&3 == 0
                const size_t idx0 =
                    ((size_t)((bh*64 + (t0 >> 5))*4 + (hd >> 4)))*512
                    + (size_t)((qv*16 + (hd & 15))*8 + jv0);
                ushort4 st;
                st.x = f2bf((acc[mi][ni][0] + bv) * oscale);
                st.y = f2bf((acc[mi][ni][1] + bv) * oscale);
                st.z = f2bf((acc[mi][ni][2] + bv) * oscale);
                st.w = f2bf((acc[mi][ni][3] + bv) * oscale);
                *(ushort4*)&((unsigned short*)Out)[idx0] = st;
            }
        }
    }
}

// Fused QKV (split form): grid (64, 24); blockIdx.y: 0-7 Q, 8-15 K, 16-23 V.
// 1536 blocks keep inter-block phase stagger (m114).
#define QSCALE (0.03125f * 1.44269504088896340736f)   // (1/sqrt(C)) * log2(e)

__global__ __launch_bounds__(256) void gemm_qkv(
    const unsigned short* __restrict__ A,
    const unsigned short* __restrict__ Wq, const unsigned short* __restrict__ Wk,
    const unsigned short* __restrict__ Wv,
    const float* __restrict__ bq, const float* __restrict__ bk,
    const float* __restrict__ bv,
    unsigned short* __restrict__ Qo, unsigned short* __restrict__ Ko,
    unsigned short* __restrict__ Vo)
{
    __shared__ __align__(16) unsigned short As[2*TM*BK];
    __shared__ __align__(16) unsigned short Bs[2*TN*BK];
    const int wi = blockIdx.y >> 3;
    const int n_base = (blockIdx.y & 7) * TN;
    const int m_base = blockIdx.x * TM;
    if (wi == 0)
        gemm_core<1>(A, Wq, bq, Qo, As, Bs, m_base, n_base, QSCALE);
    else if (wi == 1)
        gemm_core<1>(A, Wk, bk, Ko, As, Bs, m_base, n_base, 1.0f);
    else
        gemm_core<2>(A, Wv, bv, Vo, As, Bs, m_base, n_base, 1.0f);
}

__global__ __launch_bounds__(256) void gemm_out(
    const unsigned short* __restrict__ A,
    const unsigned short* __restrict__ W,
    const float* __restrict__ bias,
    float* __restrict__ Out)
{
    __shared__ __align__(16) unsigned short As[2*TM*BK];
    __shared__ __align__(16) unsigned short Bs[2*TN*BK];
    gemm_core<0>(A, W, bias, Out, As, Bs, blockIdx.x * TM, blockIdx.y * TN, 1.0f);
}

// ---------------- flash attention (causal), transposed-P scheme -------------
// S^T = mfma(A=K, B=Q); C-layout of S^T: l16 = Q-row, quad*4+r = key.
// exp -> P^T; pack pairs (v_perm RTZ) into B-operand of O^T = mfma(V^T, P^T).
// T5 setprio (m191). Strip-pair fusion (R3). Diag-half skip (R4). lsum
// tree-reduce (R5).
// R8 = R7 staging with the WIDTH BUG FIXED: one global_load_lds(16) moves
// 64 lanes x 16B = 1KB = 512 shorts, but each wave's quarter of the 8KB
// K (or V) tile is 1024 shorts -> TWO instructions per operand per wave
// (+0 and +512 shorts, global src and LDS dest shifted together). R7's
// single instruction left half of each quarter unstaged (absmax 2.9).
// 4 staging instrs per wave per iter, steady-state vmcnt(4), tail vmcnt(0).
// Sync: FBmax block-uniform; barriers uniform; WAR protected by the
// previous iteration's lgkmcnt(0) + closing barrier.
__device__ __forceinline__ void attn_tile(
    const bf16x8 kf[4][2], const bf16x8 vf[4][2],
    const bf16x8 q[4], floatx4 o[2][4], float l[2],
    bool diag, bool skiphi, int q0, int j0, int quad, int l16)
{
    #pragma unroll
    for (int sub = 0; sub < 2; ++sub) {
        const bf16x8 qx0 = q[sub*2];
        const bf16x8 qx1 = q[sub*2 + 1];

        floatx4 s[4];
        __builtin_amdgcn_s_setprio(1);
        #pragma unroll
        for (int ct = 0; ct < 2; ++ct) {
            s[ct] = (floatx4){0.f,0.f,0.f,0.f};
            s[ct] = __builtin_amdgcn_mfma_f32_16x16x32_bf16(kf[ct][0], qx0, s[ct], 0,0,0);
            s[ct] = __builtin_amdgcn_mfma_f32_16x16x32_bf16(kf[ct][1], qx1, s[ct], 0,0,0);
        }
        if (!skiphi) {
            #pragma unroll
            for (int ct = 2; ct < 4; ++ct) {
                s[ct] = (floatx4){0.f,0.f,0.f,0.f};
                s[ct] = __builtin_amdgcn_mfma_f32_16x16x32_bf16(kf[ct][0], qx0, s[ct], 0,0,0);
                s[ct] = __builtin_amdgcn_mfma_f32_16x16x32_bf16(kf[ct][1], qx1, s[ct], 0,0,0);
            }
        }
        __builtin_amdgcn_s_setprio(0);

        float p[4][4];
        float psum[4];
        const int row = q0 + sub*16 + l16;
        #pragma unroll
        for (int ct = 0; ct < 2; ++ct) {
            if (!diag) {
                #pragma unroll
                for (int r = 0; r < 4; ++r)
                    p[ct][r] = __builtin_amdgcn_exp2f(s[ct][r]);
            } else {
                #pragma unroll
                for (int r = 0; r < 4; ++r) {
                    const int key = j0 + ct*16 + quad*4 + r;
                    p[ct][r] = (key <= row) ? __builtin_amdgcn_exp2f(s[ct][r]) : 0.f;
                }
            }
            psum[ct] = (p[ct][0] + p[ct][1]) + (p[ct][2] + p[ct][3]);
        }
        if (!skiphi) {
            #pragma unroll
            for (int ct = 2; ct < 4; ++ct) {
                if (!diag) {
                    #pragma unroll
                    for (int r = 0; r < 4; ++r)
                        p[ct][r] = __builtin_amdgcn_exp2f(s[ct][r]);
                } else {
                    #pragma unroll
                    for (int r = 0; r < 4; ++r) {
                        const int key = j0 + ct*16 + quad*4 + r;
                        p[ct][r] = (key <= row) ? __builtin_amdgcn_exp2f(s[ct][r]) : 0.f;
                    }
                }
                psum[ct] = (p[ct][0] + p[ct][1]) + (p[ct][2] + p[ct][3]);
            }
            l[sub] += (psum[0] + psum[1]) + (psum[2] + psum[3]);
        } else {
            l[sub] += psum[0] + psum[1];
        }

        union { bf16x8 v; unsigned int u[4]; } pf0;
        pf0.u[0] = pk2(p[0][0], p[0][1]); pf0.u[1] = pk2(p[0][2], p[0][3]);
        pf0.u[2] = pk2(p[1][0], p[1][1]); pf0.u[3] = pk2(p[1][2], p[1][3]);

        __builtin_amdgcn_s_setprio(1);
        #pragma unroll
        for (int nt = 0; nt < 4; ++nt)
            o[sub][nt] = __builtin_amdgcn_mfma_f32_16x16x32_bf16(vf[nt][0], pf0.v, o[sub][nt], 0,0,0);
        __builtin_amdgcn_s_setprio(0);

        if (!skiphi) {
            union { bf16x8 v; unsigned int u[4]; } pf1;
            pf1.u[0] = pk2(p[2][0], p[2][1]); pf1.u[1] = pk2(p[2][2], p[2][3]);
            pf1.u[2] = pk2(p[3][0], p[3][1]); pf1.u[3] = pk2(p[3][2], p[3][3]);
            __builtin_amdgcn_s_setprio(1);
            #pragma unroll
            for (int nt = 0; nt < 4; ++nt)
                o[sub][nt] = __builtin_amdgcn_mfma_f32_16x16x32_bf16(vf[nt][1], pf1.v, o[sub][nt], 0,0,0);
            __builtin_amdgcn_s_setprio(0);
        }
    }
}

__device__ __forceinline__ void attn_store(
    unsigned short* __restrict__ Y, const floatx4 o[2][4], const float l[2],
    int q0, int b, int h, int quad, int l16)
{
    float la = l[0], lb = l[1];
    la += __shfl_xor(la, 16); la += __shfl_xor(la, 32);
    lb += __shfl_xor(lb, 16); lb += __shfl_xor(lb, 32);
    const float ia = 1.0f / la, ib = 1.0f / lb;
    const size_t Rbase = (size_t)((b*NT + q0) >> 4);
    const int cg = (quad >> 1), co = (quad & 1)*4;
    #pragma unroll
    for (int nt = 0; nt < 4; ++nt) {
        const size_t base = ((Rbase*32 + h*2 + (nt >> 1))*512)
                          + (size_t)((((nt & 1)*2 + cg)*16 + l16)*8 + co);
        ushort4 wa, wb;
        wa.x = f2bf(o[0][nt][0]*ia); wa.y = f2bf(o[0][nt][1]*ia);
        wa.z = f2bf(o[0][nt][2]*ia); wa.w = f2bf(o[0][nt][3]*ia);
        wb.x = f2bf(o[1][nt][0]*ib); wb.y = f2bf(o[1][nt][1]*ib);
        wb.z = f2bf(o[1][nt][2]*ib); wb.w = f2bf(o[1][nt][3]*ib);
        *(ushort4*)&Y[base]         = wa;
        *(ushort4*)&Y[base + 16384] = wb;   // +1 row-tile (32*512)
    }
}

// T1 XCD-grouping: 512 blocks, 1-D. bh depends only on L mod 64 so all 8
// blocks of one (b,h) share L%8 (= XCD).
__global__ __launch_bounds__(256, 2) void flash_attn(
    const unsigned short* __restrict__ Qf,
    const unsigned short* __restrict__ Kf,
    const unsigned short* __restrict__ Vf,
    unsigned short* __restrict__ Y)
{
    __shared__ __align__(16) unsigned short Ks[2][4096];   // 8KB K tile x2
    __shared__ __align__(16) unsigned short Vs[2][4096];   // 8KB V tile x2

    const int tid  = threadIdx.x;
    const int wave = tid >> 6;
    const int lane = tid & 63;
    const int L  = blockIdx.x;
    const int bh = (L & 7) * 8 + ((L >> 3) & 7);
    const int x  = L >> 6;
    const int w  = x * 4 + wave;               // 0..31
    const int stA = w, stB = 63 - w;

    const int quad = lane >> 4, l16 = lane & 15;
    const int b = bh >> 4, h = bh & (NH - 1);
    const int q0A = stA * 32, q0B = stB * 32;
    const int FA = q0A >> 6, FB = q0B >> 6;    // per-wave
    const int FBmax = (63 - 4*x) >> 1;         // block-uniform (= FB of wave 0)
    const bool skA = (q0A & 32) == 0;
    const bool skB = (q0B & 32) == 0;

    const size_t qbA = ((size_t)(bh*128 + stA*2))*1024 + (size_t)lane*8;
    const size_t qbB = ((size_t)(bh*128 + stB*2))*1024 + (size_t)lane*8;
    bf16x8 qA[4], qB[4];
    qA[0] = *(const bf16x8*)&Qf[qbA];
    qA[1] = *(const bf16x8*)&Qf[qbA + 512];
    qA[2] = *(const bf16x8*)&Qf[qbA + 1024];
    qA[3] = *(const bf16x8*)&Qf[qbA + 1536];
    qB[0] = *(const bf16x8*)&Qf[qbB];
    qB[1] = *(const bf16x8*)&Qf[qbB + 512];
    qB[2] = *(const bf16x8*)&Qf[qbB + 1024];
    qB[3] = *(const bf16x8*)&Qf[qbB + 1536];

    // per-lane global srcs for staging; each wave stages its 2KB quarter
    // via TWO 1KB instructions per operand (+0 / +512 shorts).
    const unsigned short* kg = Kf + (size_t)bh*131072 + (size_t)wave*1024 + (size_t)lane*8;
    const unsigned short* vg = Vf + (size_t)bh*131072 + (size_t)wave*1024 + (size_t)lane*8;

    floatx4 oA[2][4], oB[2][4];
    float lA[2] = {0.f, 0.f}, lB[2] = {0.f, 0.f};
    #pragma unroll
    for (int s2 = 0; s2 < 2; ++s2)
        #pragma unroll
        for (int nt = 0; nt < 4; ++nt) {
            oA[s2][nt] = (floatx4){0.f,0.f,0.f,0.f};
            oB[s2][nt] = (floatx4){0.f,0.f,0.f,0.f};
        }

    // prologue: stage tile f=0 into buf 0 (4 loads per wave)
    __builtin_amdgcn_global_load_lds(AS1(kg),       AS3(&Ks[0][wave*1024]),       16, 0, 0);
    __builtin_amdgcn_global_load_lds(AS1(kg + 512), AS3(&Ks[0][wave*1024 + 512]), 16, 0, 0);
    __builtin_amdgcn_global_load_lds(AS1(vg),       AS3(&Vs[0][wave*1024]),       16, 0, 0);
    __builtin_amdgcn_global_load_lds(AS1(vg + 512), AS3(&Vs[0][wave*1024 + 512]), 16, 0, 0);

    #pragma unroll 1
    for (int f = 0; f <= FBmax; ++f) {
        const int cur = f & 1;
        if (f < FBmax) {
            const int nb = cur ^ 1;
            const unsigned short* kn = kg + (size_t)(f+1)*4096;
            const unsigned short* vn = vg + (size_t)(f+1)*4096;
            __builtin_amdgcn_global_load_lds(AS1(kn),       AS3(&Ks[nb][wave*1024]),       16, 0, 0);
            __builtin_amdgcn_global_load_lds(AS1(kn + 512), AS3(&Ks[nb][wave*1024 + 512]), 16, 0, 0);
            __builtin_amdgcn_global_load_lds(AS1(vn),       AS3(&Vs[nb][wave*1024]),       16, 0, 0);
            __builtin_amdgcn_global_load_lds(AS1(vn + 512), AS3(&Vs[nb][wave*1024 + 512]), 16, 0, 0);
            // own 4 newest (tile f+1) stay in flight; tile f's 4 are done
            asm volatile("s_waitcnt vmcnt(4)" ::: "memory");
        } else {
            asm volatile("s_waitcnt vmcnt(0)" ::: "memory");
        }
        __builtin_amdgcn_s_barrier();          // tile f ready in buf cur

        if (f <= FB) {
            bf16x8 kf[4][2], vf[4][2];
            #pragma unroll
            for (int ct = 0; ct < 4; ++ct) {
                kf[ct][0] = *(const bf16x8*)&Ks[cur][ct*1024 + lane*8];
                kf[ct][1] = *(const bf16x8*)&Ks[cur][ct*1024 + 512 + lane*8];
            }
            #pragma unroll
            for (int nt = 0; nt < 4; ++nt) {
                vf[nt][0] = *(const bf16x8*)&Vs[cur][nt*512 + lane*8];
                vf[nt][1] = *(const bf16x8*)&Vs[cur][2048 + nt*512 + lane*8];
            }
            const int j0 = f * 64;
            if (f <= FA)
                attn_tile(kf, vf, qA, oA, lA, f == FA, (f == FA) && skA,
                          q0A, j0, quad, l16);
            attn_tile(kf, vf, qB, oB, lB, f == FB, (f == FB) && skB,
                      q0B, j0, quad, l16);
        }
        // drain LDS reads before other waves overwrite this buffer next iter
        asm volatile("s_waitcnt lgkmcnt(0)" ::: "memory");
        __builtin_amdgcn_s_barrier();          // all waves done with buf cur
    }

    attn_store(Y, oA, lA, q0A, b, h, quad, l16);
    attn_store(Y, oB, lB, q0B, b, h, quad, l16);
}

// ---------------- launch ----------------
extern "C" void kernel_launch(void* const* d_in, const int* in_sizes, int n_in,
                              void* d_out, int out_size, void* d_ws, size_t ws_size,
                              hipStream_t stream) {
    const float* x  = (const float*)d_in[0];
    const float* Wq = (const float*)d_in[1];
    const float* bq = (const float*)d_in[2];
    const float* Wk = (const float*)d_in[3];
    const float* bk = (const float*)d_in[4];
    const float* Wv = (const float*)d_in[5];
    const float* bv = (const float*)d_in[6];
    const float* Wo = (const float*)d_in[7];
    const float* bo = (const float*)d_in[8];

    char* ws = (char*)d_ws;
    size_t off = 0;
    auto alloc = [&](size_t bytes) -> void* {
        void* p = ws + off;
        off += (bytes + 255) & ~(size_t)255;
        return p;
    };
    unsigned short* xb  = (unsigned short*)alloc((size_t)NM * NC * 2);
    unsigned short* Wqb = (unsigned short*)alloc((size_t)NC * NC * 2);
    unsigned short* Wkb = (unsigned short*)alloc((size_t)NC * NC * 2);
    unsigned short* Wvb = (unsigned short*)alloc((size_t)NC * NC * 2);
    unsigned short* Wob = (unsigned short*)alloc((size_t)NC * NC * 2);
    unsigned short* Qb  = (unsigned short*)alloc((size_t)NM * NC * 2);
    unsigned short* Kb  = (unsigned short*)alloc((size_t)NM * NC * 2);
    unsigned short* Vtb = (unsigned short*)alloc((size_t)NM * NC * 2);
    unsigned short* Yb  = (unsigned short*)alloc((size_t)NM * NC * 2);

    // 16384 x-tiles + 4*2048 weight tiles = 24576 wave-tiles
    cast_all<<<(24576*64)/256, 256, 0, stream>>>(
        x, Wq, Wk, Wv, Wo, xb, Wqb, Wkb, Wvb, Wob);

    gemm_qkv<<<dim3(NM / TM, 24), 256, 0, stream>>>(
        xb, Wqb, Wkb, Wvb, bq, bk, bv, Qb, Kb, Vtb);

    flash_attn<<<dim3(512), 256, 0, stream>>>(Qb, Kb, Vtb, Yb);

    gemm_out<<<dim3(NM / TM, NC / TN), 256, 0, stream>>>(Yb, Wob, bo, (float*)d_out);
}

// Round 9
// 230.746 us; speedup vs baseline: 1.0533x; 1.0533x over previous
//
#include <hip/hip_runtime.h>
#include <hip/hip_bf16.h>
#include <stdint.h>

// Problem constants
#define NB 4
#define NT 2048
#define NC 1024
#define NH 16
#define NHD 64
#define NM (NB*NT)   // 8192 rows

typedef __attribute__((ext_vector_type(8))) __bf16 bf16x8;
typedef __attribute__((ext_vector_type(4))) float floatx4;
typedef __attribute__((ext_vector_type(8))) unsigned short ushortx8;

#define AS1(p) ((const __attribute__((address_space(1))) void*)(p))
#define AS3(p) ((__attribute__((address_space(3))) void*)(p))

__device__ __forceinline__ unsigned short f2bf(float f) {
    union { float f; unsigned int u; } v; v.f = f;
    unsigned int u = v.u;
    return (unsigned short)((u + 0x7FFFu + ((u >> 16) & 1u)) >> 16);
}
// pack two fp32 -> (bf16(hi)<<16)|bf16(lo), RTZ, single v_perm_b32
__device__ __forceinline__ unsigned int pk2(float lo, float hi) {
    union { float f; unsigned int u; } a, b; a.f = hi; b.f = lo;
    return __builtin_amdgcn_perm(a.u, b.u, 0x07060302u);
}

// ===== fragment-tiled layout (for all GEMM operands) =====
// matrix (rows x 1024 cols) stored as 16x32 tiles of 512 shorts:
//   tile (R=row/16, C=col/32) at offset (R*32 + C)*512
//   element (r=row&15, c=col&31) at ((c>>3)*16 + r)*8 + (c&7)

// ---------------- merged cast fp32 -> bf16, fragment-tiled ------------------
__global__ void cast_all(const float* __restrict__ x,
                         const float* __restrict__ w0, const float* __restrict__ w1,
                         const float* __restrict__ w2, const float* __restrict__ w3,
                         unsigned short* __restrict__ xo,
                         unsigned short* __restrict__ o0, unsigned short* __restrict__ o1,
                         unsigned short* __restrict__ o2, unsigned short* __restrict__ o3)
{
    const int wid  = (blockIdx.x * blockDim.x + threadIdx.x) >> 6;
    const int lane = threadIdx.x & 63;
    const float* in; unsigned short* out; int tile;
    if (wid < 16384) { in = x; out = xo; tile = wid; }
    else {
        const int t = wid - 16384;
        tile = t & 2047;
        switch (t >> 11) {
            case 0: in = w0; out = o0; break;
            case 1: in = w1; out = o1; break;
            case 2: in = w2; out = o2; break;
            default: in = w3; out = o3; break;
        }
    }
    const int R = tile >> 5, C = tile & 31;
    const float* src = in + ((size_t)(R*16 + (lane >> 2)))*1024 + C*32 + (lane & 3)*8;
    const floatx4 v0 = *(const floatx4*)src;
    const floatx4 v1 = *(const floatx4*)(src + 4);
    ushortx8 o;
    o[0] = f2bf(v0[0]); o[1] = f2bf(v0[1]); o[2] = f2bf(v0[2]); o[3] = f2bf(v0[3]);
    o[4] = f2bf(v1[0]); o[5] = f2bf(v1[1]); o[6] = f2bf(v1[2]); o[7] = f2bf(v1[3]);
    *(ushortx8*)&out[(size_t)tile*512 + (((lane & 3)*16 + (lane >> 2)))*8] = o;
}

// ---------------- GEMM core: Out = (A @ W^T + bias) * oscale ----------------
// A, W fragment-tiled, K=1024. BK=32, 128x128 tile, 4 waves, dbuf 32KB LDS,
// raw s_barrier + counted vmcnt(4) (R4 structure — best measured).
// COMPONENT LEDGER (unbundled, R9):
//   gemm_qkv: split dbuf 73.4us (R4) < split tri-buf 74.6 (R6) < merged 90 (R5)
//   gemm_out: dbuf (R4/R8) beats tri-buf (R6, ~+17us: 48KB LDS -> 3 blk/CU)
//   attn: register loads (R5) beat LDS staging (R8, ~+24us: lockstep
//         barriers serialized independent waves; K/V already L1-shared)
// This round = best-of-each, nothing new bundled.
// MODE 0: Out fp32 row-major MxN (final projection)          [mfma(X, W)]
// MODE 1: Out bf16 Q/K fragment order, swapped operands      [mfma(W, X)]
// MODE 2: Out bf16 V^T key-permuted A-frag order             [mfma(X, W)]
#define TM 128
#define TN 128
#define BK 32

template<int MODE>
__device__ __forceinline__ void gemm_core(
    const unsigned short* __restrict__ A,
    const unsigned short* __restrict__ W,
    const float* __restrict__ bias,
    void* __restrict__ Out,
    unsigned short* As, unsigned short* Bs,   // each 2 x 4096 shorts (dbuf)
    int m_base, int n_base, float oscale)
{
    const int tid  = threadIdx.x;
    const int lane = tid & 63;
    const int wv   = tid >> 6;
    const int quad = lane >> 4;
    const int l16  = lane & 15;
    const int wm = (wv >> 1) * 64;
    const int wn = (wv & 1) * 64;

    floatx4 acc[4][4];
    #pragma unroll
    for (int i = 0; i < 4; ++i)
        #pragma unroll
        for (int j = 0; j < 4; ++j)
            acc[i][j] = (floatx4){0.f, 0.f, 0.f, 0.f};

    const int kct = NC >> 5;   // 32 k-tiles

    const unsigned short* At = A + ((size_t)((m_base >> 4) + wv*2) * kct) * 512 + (size_t)lane*8;
    const unsigned short* Wt = W + ((size_t)((n_base >> 4) + wv*2) * kct) * 512 + (size_t)lane*8;
    const size_t rstride = (size_t)kct * 512;

    // prologue: stage k-tile 0 into buf 0 (4 loads per wave)
    #pragma unroll
    for (int i = 0; i < 2; ++i) {
        __builtin_amdgcn_global_load_lds(AS1(At + i*rstride),
                                         AS3(&As[(wv*2 + i)*512]), 16, 0, 0);
        __builtin_amdgcn_global_load_lds(AS1(Wt + i*rstride),
                                         AS3(&Bs[(wv*2 + i)*512]), 16, 0, 0);
    }

    #pragma unroll 1
    for (int kt = 0; kt < 32; ++kt) {
        const int cur = (kt & 1) << 12;        // 0 / 4096 shorts
        const int nxt = 4096 - cur;
        if (kt < 31) {
            #pragma unroll
            for (int i = 0; i < 2; ++i) {
                __builtin_amdgcn_global_load_lds(
                    AS1(At + (size_t)(kt+1)*512 + i*rstride),
                    AS3(&As[nxt + (wv*2 + i)*512]), 16, 0, 0);
                __builtin_amdgcn_global_load_lds(
                    AS1(Wt + (size_t)(kt+1)*512 + i*rstride),
                    AS3(&Bs[nxt + (wv*2 + i)*512]), 16, 0, 0);
            }
            // own 4 newest (tile kt+1) stay in flight; tile kt's 4 are done
            asm volatile("s_waitcnt vmcnt(4)" ::: "memory");
        } else {
            asm volatile("s_waitcnt vmcnt(0)" ::: "memory");
        }
        __builtin_amdgcn_s_barrier();          // tile kt ready in buf cur

        bf16x8 af[4], bfr[4];
        #pragma unroll
        for (int mi = 0; mi < 4; ++mi)
            af[mi] = *(const bf16x8*)&As[cur + ((wv >> 1)*4 + mi)*512 + lane*8];
        #pragma unroll
        for (int ni = 0; ni < 4; ++ni)
            bfr[ni] = *(const bf16x8*)&Bs[cur + ((wv & 1)*4 + ni)*512 + lane*8];

        #pragma unroll
        for (int mi = 0; mi < 4; ++mi)
            #pragma unroll
            for (int ni = 0; ni < 4; ++ni) {
                if (MODE == 1)   // swapped: d on quad axis, t on l16
                    acc[mi][ni] = __builtin_amdgcn_mfma_f32_16x16x32_bf16(
                        bfr[ni], af[mi], acc[mi][ni], 0, 0, 0);
                else
                    acc[mi][ni] = __builtin_amdgcn_mfma_f32_16x16x32_bf16(
                        af[mi], bfr[ni], acc[mi][ni], 0, 0, 0);
            }
        __builtin_amdgcn_s_barrier();          // all waves done reading buf cur
    }

    // epilogue
    #pragma unroll
    for (int mi = 0; mi < 4; ++mi) {
        #pragma unroll
        for (int ni = 0; ni < 4; ++ni) {
            if (MODE == 0) {
                const int col = n_base + wn + ni*16 + l16;
                const float bv = bias[col & 1023];
                #pragma unroll
                for (int r = 0; r < 4; ++r) {
                    const int row = m_base + wm + mi*16 + quad*4 + r;
                    ((float*)Out)[(size_t)row * NC + col] =
                        (acc[mi][ni][r] + bv) * oscale;
                }
            } else if (MODE == 1) {
                const int d0 = n_base + wn + ni*16 + quad*4;
                const int t  = m_base + wm + mi*16 + l16;
                const float4 b4 = *(const float4*)&bias[d0];
                const int bb = t >> 11, tt = t & (NT - 1);
                const int h  = (d0 >> 6) & (NH - 1), dd0 = d0 & 63;
                const int bh = bb * NH + h;
                const size_t idx0 =
                    ((size_t)((bh*128 + (tt >> 4))*2 + (dd0 >> 5)))*512
                    + (size_t)((((dd0 >> 3) & 3)*16 + (tt & 15))*8 + (dd0 & 7));
                ushort4 st;
                st.x = f2bf((acc[mi][ni][0] + b4.x) * oscale);
                st.y = f2bf((acc[mi][ni][1] + b4.y) * oscale);
                st.z = f2bf((acc[mi][ni][2] + b4.z) * oscale);
                st.w = f2bf((acc[mi][ni][3] + b4.w) * oscale);
                *(ushort4*)&((unsigned short*)Out)[idx0] = st;
            } else {
                const int col = n_base + wn + ni*16 + l16;
                const float bv = bias[col & 1023];
                const int row0 = m_base + wm + mi*16 + quad*4;
                const int bb = row0 >> 11, t0 = row0 & (NT - 1);
                const int h  = (col >> 6) & (NH - 1), hd = col & 63;
                const int bh = bb * NH + h;
                const int tk0 = t0 & 31;
                const int qv  = (tk0 >> 2) & 3;
                const int jv0 = (tk0 >> 4) << 2;      // tk0&3 == 0
                const size_t idx0 =
                    ((size_t)((bh*64 + (t0 >> 5))*4 + (hd >> 4)))*512
                    + (size_t)((qv*16 + (hd & 15))*8 + jv0);
                ushort4 st;
                st.x = f2bf((acc[mi][ni][0] + bv) * oscale);
                st.y = f2bf((acc[mi][ni][1] + bv) * oscale);
                st.z = f2bf((acc[mi][ni][2] + bv) * oscale);
                st.w = f2bf((acc[mi][ni][3] + bv) * oscale);
                *(ushort4*)&((unsigned short*)Out)[idx0] = st;
            }
        }
    }
}

// Fused QKV (split form): grid (64, 24); blockIdx.y: 0-7 Q, 8-15 K, 16-23 V.
// 1536 blocks keep inter-block phase stagger (m114).
#define QSCALE (0.03125f * 1.44269504088896340736f)   // (1/sqrt(C)) * log2(e)

__global__ __launch_bounds__(256) void gemm_qkv(
    const unsigned short* __restrict__ A,
    const unsigned short* __restrict__ Wq, const unsigned short* __restrict__ Wk,
    const unsigned short* __restrict__ Wv,
    const float* __restrict__ bq, const float* __restrict__ bk,
    const float* __restrict__ bv,
    unsigned short* __restrict__ Qo, unsigned short* __restrict__ Ko,
    unsigned short* __restrict__ Vo)
{
    __shared__ __align__(16) unsigned short As[2*TM*BK];
    __shared__ __align__(16) unsigned short Bs[2*TN*BK];
    const int wi = blockIdx.y >> 3;
    const int n_base = (blockIdx.y & 7) * TN;
    const int m_base = blockIdx.x * TM;
    if (wi == 0)
        gemm_core<1>(A, Wq, bq, Qo, As, Bs, m_base, n_base, QSCALE);
    else if (wi == 1)
        gemm_core<1>(A, Wk, bk, Ko, As, Bs, m_base, n_base, 1.0f);
    else
        gemm_core<2>(A, Wv, bv, Vo, As, Bs, m_base, n_base, 1.0f);
}

__global__ __launch_bounds__(256) void gemm_out(
    const unsigned short* __restrict__ A,
    const unsigned short* __restrict__ W,
    const float* __restrict__ bias,
    float* __restrict__ Out)
{
    __shared__ __align__(16) unsigned short As[2*TM*BK];
    __shared__ __align__(16) unsigned short Bs[2*TN*BK];
    gemm_core<0>(A, W, bias, Out, As, Bs, blockIdx.x * TM, blockIdx.y * TN, 1.0f);
}

// ---------------- flash attention (causal), transposed-P scheme -------------
// S^T = mfma(A=K, B=Q); C-layout of S^T: l16 = Q-row, quad*4+r = key.
// exp -> P^T; pack pairs (v_perm RTZ) into B-operand of O^T = mfma(V^T, P^T).
// REGISTER K/V loads (no LDS): the block's 4 waves read the same K/V lines,
// served by L1 (same CU) — measured faster than LDS staging by ~24us (R8).
// T5 setprio (m191). Strip-pair fusion (R3). Diag-half skip (R4). lsum
// tree-reduce (R5).
__device__ __forceinline__ void attn_tile(
    const bf16x8 kf[4][2], const bf16x8 vf[4][2],
    const bf16x8 q[4], floatx4 o[2][4], float l[2],
    bool diag, bool skiphi, int q0, int j0, int quad, int l16)
{
    #pragma unroll
    for (int sub = 0; sub < 2; ++sub) {
        const bf16x8 qx0 = q[sub*2];
        const bf16x8 qx1 = q[sub*2 + 1];

        floatx4 s[4];
        __builtin_amdgcn_s_setprio(1);
        #pragma unroll
        for (int ct = 0; ct < 2; ++ct) {
            s[ct] = (floatx4){0.f,0.f,0.f,0.f};
            s[ct] = __builtin_amdgcn_mfma_f32_16x16x32_bf16(kf[ct][0], qx0, s[ct], 0,0,0);
            s[ct] = __builtin_amdgcn_mfma_f32_16x16x32_bf16(kf[ct][1], qx1, s[ct], 0,0,0);
        }
        if (!skiphi) {
            #pragma unroll
            for (int ct = 2; ct < 4; ++ct) {
                s[ct] = (floatx4){0.f,0.f,0.f,0.f};
                s[ct] = __builtin_amdgcn_mfma_f32_16x16x32_bf16(kf[ct][0], qx0, s[ct], 0,0,0);
                s[ct] = __builtin_amdgcn_mfma_f32_16x16x32_bf16(kf[ct][1], qx1, s[ct], 0,0,0);
            }
        }
        __builtin_amdgcn_s_setprio(0);

        float p[4][4];
        float psum[4];
        const int row = q0 + sub*16 + l16;
        #pragma unroll
        for (int ct = 0; ct < 2; ++ct) {
            if (!diag) {
                #pragma unroll
                for (int r = 0; r < 4; ++r)
                    p[ct][r] = __builtin_amdgcn_exp2f(s[ct][r]);
            } else {
                #pragma unroll
                for (int r = 0; r < 4; ++r) {
                    const int key = j0 + ct*16 + quad*4 + r;
                    p[ct][r] = (key <= row) ? __builtin_amdgcn_exp2f(s[ct][r]) : 0.f;
                }
            }
            psum[ct] = (p[ct][0] + p[ct][1]) + (p[ct][2] + p[ct][3]);
        }
        if (!skiphi) {
            #pragma unroll
            for (int ct = 2; ct < 4; ++ct) {
                if (!diag) {
                    #pragma unroll
                    for (int r = 0; r < 4; ++r)
                        p[ct][r] = __builtin_amdgcn_exp2f(s[ct][r]);
                } else {
                    #pragma unroll
                    for (int r = 0; r < 4; ++r) {
                        const int key = j0 + ct*16 + quad*4 + r;
                        p[ct][r] = (key <= row) ? __builtin_amdgcn_exp2f(s[ct][r]) : 0.f;
                    }
                }
                psum[ct] = (p[ct][0] + p[ct][1]) + (p[ct][2] + p[ct][3]);
            }
            l[sub] += (psum[0] + psum[1]) + (psum[2] + psum[3]);
        } else {
            l[sub] += psum[0] + psum[1];
        }

        union { bf16x8 v; unsigned int u[4]; } pf0;
        pf0.u[0] = pk2(p[0][0], p[0][1]); pf0.u[1] = pk2(p[0][2], p[0][3]);
        pf0.u[2] = pk2(p[1][0], p[1][1]); pf0.u[3] = pk2(p[1][2], p[1][3]);

        __builtin_amdgcn_s_setprio(1);
        #pragma unroll
        for (int nt = 0; nt < 4; ++nt)
            o[sub][nt] = __builtin_amdgcn_mfma_f32_16x16x32_bf16(vf[nt][0], pf0.v, o[sub][nt], 0,0,0);
        __builtin_amdgcn_s_setprio(0);

        if (!skiphi) {
            union { bf16x8 v; unsigned int u[4]; } pf1;
            pf1.u[0] = pk2(p[2][0], p[2][1]); pf1.u[1] = pk2(p[2][2], p[2][3]);
            pf1.u[2] = pk2(p[3][0], p[3][1]); pf1.u[3] = pk2(p[3][2], p[3][3]);
            __builtin_amdgcn_s_setprio(1);
            #pragma unroll
            for (int nt = 0; nt < 4; ++nt)
                o[sub][nt] = __builtin_amdgcn_mfma_f32_16x16x32_bf16(vf[nt][1], pf1.v, o[sub][nt], 0,0,0);
            __builtin_amdgcn_s_setprio(0);
        }
    }
}

__device__ __forceinline__ void attn_store(
    unsigned short* __restrict__ Y, const floatx4 o[2][4], const float l[2],
    int q0, int b, int h, int quad, int l16)
{
    float la = l[0], lb = l[1];
    la += __shfl_xor(la, 16); la += __shfl_xor(la, 32);
    lb += __shfl_xor(lb, 16); lb += __shfl_xor(lb, 32);
    const float ia = 1.0f / la, ib = 1.0f / lb;
    const size_t Rbase = (size_t)((b*NT + q0) >> 4);
    const int cg = (quad >> 1), co = (quad & 1)*4;
    #pragma unroll
    for (int nt = 0; nt < 4; ++nt) {
        const size_t base = ((Rbase*32 + h*2 + (nt >> 1))*512)
                          + (size_t)((((nt & 1)*2 + cg)*16 + l16)*8 + co);
        ushort4 wa, wb;
        wa.x = f2bf(o[0][nt][0]*ia); wa.y = f2bf(o[0][nt][1]*ia);
        wa.z = f2bf(o[0][nt][2]*ia); wa.w = f2bf(o[0][nt][3]*ia);
        wb.x = f2bf(o[1][nt][0]*ib); wb.y = f2bf(o[1][nt][1]*ib);
        wb.z = f2bf(o[1][nt][2]*ib); wb.w = f2bf(o[1][nt][3]*ib);
        *(ushort4*)&Y[base]         = wa;
        *(ushort4*)&Y[base + 16384] = wb;   // +1 row-tile (32*512)
    }
}

__device__ __forceinline__ void attn_pair(
    const unsigned short* __restrict__ Qf,
    const unsigned short* __restrict__ Kf,
    const unsigned short* __restrict__ Vf,
    unsigned short* __restrict__ Y,
    int bh, int stA, int stB, int lane)
{
    const int quad = lane >> 4, l16 = lane & 15;
    const int b = bh >> 4, h = bh & (NH - 1);
    const int q0A = stA * 32, q0B = stB * 32;
    const int FA = q0A >> 6, FB = q0B >> 6;    // FA < FB always (stA<32<=stB)
    const bool skA = (q0A & 32) == 0;          // even strip: diag upper half dead
    const bool skB = (q0B & 32) == 0;

    const size_t qbA = ((size_t)(bh*128 + stA*2))*1024 + (size_t)lane*8;
    const size_t qbB = ((size_t)(bh*128 + stB*2))*1024 + (size_t)lane*8;
    bf16x8 qA[4], qB[4];
    qA[0] = *(const bf16x8*)&Qf[qbA];
    qA[1] = *(const bf16x8*)&Qf[qbA + 512];
    qA[2] = *(const bf16x8*)&Qf[qbA + 1024];
    qA[3] = *(const bf16x8*)&Qf[qbA + 1536];
    qB[0] = *(const bf16x8*)&Qf[qbB];
    qB[1] = *(const bf16x8*)&Qf[qbB + 512];
    qB[2] = *(const bf16x8*)&Qf[qbB + 1024];
    qB[3] = *(const bf16x8*)&Qf[qbB + 1536];

    const unsigned short* kp = Kf + (size_t)bh*131072 + (size_t)lane*8;
    const unsigned short* vp = Vf + (size_t)bh*131072 + (size_t)lane*8;

    floatx4 oA[2][4], oB[2][4];
    float lA[2] = {0.f, 0.f}, lB[2] = {0.f, 0.f};
    #pragma unroll
    for (int s2 = 0; s2 < 2; ++s2)
        #pragma unroll
        for (int nt = 0; nt < 4; ++nt) {
            oA[s2][nt] = (floatx4){0.f,0.f,0.f,0.f};
            oB[s2][nt] = (floatx4){0.f,0.f,0.f,0.f};
        }

    for (int f = 0; f <= FB; ++f) {
        const int j0 = f * 64;
        bf16x8 kf[4][2], vf[4][2];
        const unsigned short* kt = kp + (size_t)f * 4096;
        #pragma unroll
        for (int ct = 0; ct < 4; ++ct) {
            kf[ct][0] = *(const bf16x8*)&kt[ct*1024];
            kf[ct][1] = *(const bf16x8*)&kt[ct*1024 + 512];
        }
        const unsigned short* vt = vp + (size_t)f * 4096;
        #pragma unroll
        for (int nt = 0; nt < 4; ++nt) {
            vf[nt][0] = *(const bf16x8*)&vt[nt*512];
            vf[nt][1] = *(const bf16x8*)&vt[2048 + nt*512];
        }

        if (f <= FA)
            attn_tile(kf, vf, qA, oA, lA, f == FA, (f == FA) && skA,
                      q0A, j0, quad, l16);
        attn_tile(kf, vf, qB, oB, lB, f == FB, (f == FB) && skB,
                  q0B, j0, quad, l16);
    }

    attn_store(Y, oA, lA, q0A, b, h, quad, l16);
    attn_store(Y, oB, lB, q0B, b, h, quad, l16);
}

// T1 XCD-grouping: 512 blocks, 1-D. bh depends only on L mod 64 so all 8
// blocks of one (b,h) share L%8 (= XCD): each XCD serves 8 heads' K/V
// (4MB) from its own L2.
__global__ __launch_bounds__(256, 2) void flash_attn(
    const unsigned short* __restrict__ Qf,
    const unsigned short* __restrict__ Kf,
    const unsigned short* __restrict__ Vf,
    unsigned short* __restrict__ Y)
{
    const int tid  = threadIdx.x;
    const int wave = tid >> 6;
    const int lane = tid & 63;
    const int L  = blockIdx.x;
    const int bh = (L & 7) * 8 + ((L >> 3) & 7);
    const int x  = L >> 6;
    const int w  = x * 4 + wave;   // 0..31
    attn_pair(Qf, Kf, Vf, Y, bh, w, 63 - w, lane);
}

// ---------------- launch ----------------
extern "C" void kernel_launch(void* const* d_in, const int* in_sizes, int n_in,
                              void* d_out, int out_size, void* d_ws, size_t ws_size,
                              hipStream_t stream) {
    const float* x  = (const float*)d_in[0];
    const float* Wq = (const float*)d_in[1];
    const float* bq = (const float*)d_in[2];
    const float* Wk = (const float*)d_in[3];
    const float* bk = (const float*)d_in[4];
    const float* Wv = (const float*)d_in[5];
    const float* bv = (const float*)d_in[6];
    const float* Wo = (const float*)d_in[7];
    const float* bo = (const float*)d_in[8];

    char* ws = (char*)d_ws;
    size_t off = 0;
    auto alloc = [&](size_t bytes) -> void* {
        void* p = ws + off;
        off += (bytes + 255) & ~(size_t)255;
        return p;
    };
    unsigned short* xb  = (unsigned short*)alloc((size_t)NM * NC * 2);
    unsigned short* Wqb = (unsigned short*)alloc((size_t)NC * NC * 2);
    unsigned short* Wkb = (unsigned short*)alloc((size_t)NC * NC * 2);
    unsigned short* Wvb = (unsigned short*)alloc((size_t)NC * NC * 2);
    unsigned short* Wob = (unsigned short*)alloc((size_t)NC * NC * 2);
    unsigned short* Qb  = (unsigned short*)alloc((size_t)NM * NC * 2);
    unsigned short* Kb  = (unsigned short*)alloc((size_t)NM * NC * 2);
    unsigned short* Vtb = (unsigned short*)alloc((size_t)NM * NC * 2);
    unsigned short* Yb  = (unsigned short*)alloc((size_t)NM * NC * 2);

    // 16384 x-tiles + 4*2048 weight tiles = 24576 wave-tiles
    cast_all<<<(24576*64)/256, 256, 0, stream>>>(
        x, Wq, Wk, Wv, Wo, xb, Wqb, Wkb, Wvb, Wob);

    gemm_qkv<<<dim3(NM / TM, 24), 256, 0, stream>>>(
        xb, Wqb, Wkb, Wvb, bq, bk, bv, Qb, Kb, Vtb);

    flash_attn<<<dim3(512), 256, 0, stream>>>(Qb, Kb, Vtb, Yb);

    gemm_out<<<dim3(NM / TM, NC / TN), 256, 0, stream>>>(Yb, Wob, bo, (float*)d_out);
}

// Round 10
// 230.702 us; speedup vs baseline: 1.0535x; 1.0002x over previous
//
#include <hip/hip_runtime.h>
#include <hip/hip_bf16.h>
#include <stdint.h>

// Problem constants
#define NB 4
#define NT 2048
#define NC 1024
#define NH 16
#define NHD 64
#define NM (NB*NT)   // 8192 rows

typedef __attribute__((ext_vector_type(8))) __bf16 bf16x8;
typedef __attribute__((ext_vector_type(4))) float floatx4;
typedef __attribute__((ext_vector_type(8))) unsigned short ushortx8;

#define AS1(p) ((const __attribute__((address_space(1))) void*)(p))
#define AS3(p) ((__attribute__((address_space(3))) void*)(p))

__device__ __forceinline__ unsigned short f2bf(float f) {
    union { float f; unsigned int u; } v; v.f = f;
    unsigned int u = v.u;
    return (unsigned short)((u + 0x7FFFu + ((u >> 16) & 1u)) >> 16);
}
// pack two fp32 -> (bf16(hi)<<16)|bf16(lo), RTZ, single v_perm_b32
__device__ __forceinline__ unsigned int pk2(float lo, float hi) {
    union { float f; unsigned int u; } a, b; a.f = hi; b.f = lo;
    return __builtin_amdgcn_perm(a.u, b.u, 0x07060302u);
}

// ===== fragment-tiled layout (for all GEMM operands) =====
// matrix (rows x 1024 cols) stored as 16x32 tiles of 512 shorts:
//   tile (R=row/16, C=col/32) at offset (R*32 + C)*512
//   element (r=row&15, c=col&31) at ((c>>3)*16 + r)*8 + (c&7)

// ---------------- merged cast fp32 -> bf16, fragment-tiled ------------------
__global__ void cast_all(const float* __restrict__ x,
                         const float* __restrict__ w0, const float* __restrict__ w1,
                         const float* __restrict__ w2, const float* __restrict__ w3,
                         unsigned short* __restrict__ xo,
                         unsigned short* __restrict__ o0, unsigned short* __restrict__ o1,
                         unsigned short* __restrict__ o2, unsigned short* __restrict__ o3)
{
    const int wid  = (blockIdx.x * blockDim.x + threadIdx.x) >> 6;
    const int lane = threadIdx.x & 63;
    const float* in; unsigned short* out; int tile;
    if (wid < 16384) { in = x; out = xo; tile = wid; }
    else {
        const int t = wid - 16384;
        tile = t & 2047;
        switch (t >> 11) {
            case 0: in = w0; out = o0; break;
            case 1: in = w1; out = o1; break;
            case 2: in = w2; out = o2; break;
            default: in = w3; out = o3; break;
        }
    }
    const int R = tile >> 5, C = tile & 31;
    const float* src = in + ((size_t)(R*16 + (lane >> 2)))*1024 + C*32 + (lane & 3)*8;
    const floatx4 v0 = *(const floatx4*)src;
    const floatx4 v1 = *(const floatx4*)(src + 4);
    ushortx8 o;
    o[0] = f2bf(v0[0]); o[1] = f2bf(v0[1]); o[2] = f2bf(v0[2]); o[3] = f2bf(v0[3]);
    o[4] = f2bf(v1[0]); o[5] = f2bf(v1[1]); o[6] = f2bf(v1[2]); o[7] = f2bf(v1[3]);
    *(ushortx8*)&out[(size_t)tile*512 + (((lane & 3)*16 + (lane >> 2)))*8] = o;
}

// ---------------- GEMM core: Out = (A @ W^T + bias) * oscale ----------------
// A, W fragment-tiled, K=1024. BK=32, TM=128 x TN_ tile, 4 waves, dbuf LDS,
// raw s_barrier + counted vmcnt (R4 structure — best measured).
// R10: TN_ templated. gemm_qkv keeps TN_=128 (byte-identical to R9).
// gemm_out moves to TN_=64 -> grid (64,16) = 1024 blocks = 4/CU: it was the
// only GEMM at 2 blocks/CU, and per the R5/m114 lesson this latency-bound
// structure needs inter-block stagger; its per-FLOP time was ~2x gemm_qkv's.
// COMPONENT LEDGER:
//   gemm_qkv: split dbuf 73.4us (R4/R9) < tri-buf 74.6 (R6) < merged 90 (R5)
//   attn: register K/V (R5/R9) beats LDS staging (R8, +24us)
//   gemm_out: dbuf @TN=128/512blk baseline; this round tests 4/CU
// MODE 0: Out fp32 row-major MxN (final projection)          [mfma(X, W)]
// MODE 1: Out bf16 Q/K fragment order, swapped operands      [mfma(W, X)]
// MODE 2: Out bf16 V^T key-permuted A-frag order             [mfma(X, W)]
#define TM 128
#define BK 32

template<int MODE, int TN_>
__device__ __forceinline__ void gemm_core(
    const unsigned short* __restrict__ A,
    const unsigned short* __restrict__ W,
    const float* __restrict__ bias,
    void* __restrict__ Out,
    unsigned short* As, unsigned short* Bs,   // dbuf: As 2x4096, Bs 2x(TN_*32)
    int m_base, int n_base, float oscale)
{
    constexpr int NI  = TN_ / 32;       // n-frag tiles per wave (4 or 2)
    constexpr int TB4 = TN_ / 64;       // B-tiles staged per wave (2 or 1)
    constexpr int BHALF = TN_ * 32;     // shorts per B buffer half

    const int tid  = threadIdx.x;
    const int lane = tid & 63;
    const int wv   = tid >> 6;
    const int quad = lane >> 4;
    const int l16  = lane & 15;
    const int wm = (wv >> 1) * 64;
    const int wn = (wv & 1) * (TN_ / 2);

    floatx4 acc[4][NI];
    #pragma unroll
    for (int i = 0; i < 4; ++i)
        #pragma unroll
        for (int j = 0; j < NI; ++j)
            acc[i][j] = (floatx4){0.f, 0.f, 0.f, 0.f};

    const int kct = NC >> 5;   // 32 k-tiles

    const unsigned short* At = A + ((size_t)((m_base >> 4) + wv*2) * kct) * 512 + (size_t)lane*8;
    const unsigned short* Wt = W + ((size_t)((n_base >> 4) + wv*TB4) * kct) * 512 + (size_t)lane*8;
    const size_t rstride = (size_t)kct * 512;

    // prologue: stage k-tile 0 into buf 0 (2 A + TB4 B loads per wave)
    #pragma unroll
    for (int i = 0; i < 2; ++i)
        __builtin_amdgcn_global_load_lds(AS1(At + i*rstride),
                                         AS3(&As[(wv*2 + i)*512]), 16, 0, 0);
    #pragma unroll
    for (int i = 0; i < TB4; ++i)
        __builtin_amdgcn_global_load_lds(AS1(Wt + i*rstride),
                                         AS3(&Bs[(wv*TB4 + i)*512]), 16, 0, 0);

    #pragma unroll 1
    for (int kt = 0; kt < 32; ++kt) {
        const int curA = (kt & 1) ? 4096 : 0;
        const int nxtA = 4096 - curA;
        const int curB = (kt & 1) ? BHALF : 0;
        const int nxtB = BHALF - curB;
        if (kt < 31) {
            #pragma unroll
            for (int i = 0; i < 2; ++i)
                __builtin_amdgcn_global_load_lds(
                    AS1(At + (size_t)(kt+1)*512 + i*rstride),
                    AS3(&As[nxtA + (wv*2 + i)*512]), 16, 0, 0);
            #pragma unroll
            for (int i = 0; i < TB4; ++i)
                __builtin_amdgcn_global_load_lds(
                    AS1(Wt + (size_t)(kt+1)*512 + i*rstride),
                    AS3(&Bs[nxtB + (wv*TB4 + i)*512]), 16, 0, 0);
            // own (2+TB4) newest (tile kt+1) stay in flight; tile kt done
            if constexpr (TN_ == 128)
                asm volatile("s_waitcnt vmcnt(4)" ::: "memory");
            else
                asm volatile("s_waitcnt vmcnt(3)" ::: "memory");
        } else {
            asm volatile("s_waitcnt vmcnt(0)" ::: "memory");
        }
        __builtin_amdgcn_s_barrier();          // tile kt ready in buf cur

        bf16x8 af[4], bfr[NI];
        #pragma unroll
        for (int mi = 0; mi < 4; ++mi)
            af[mi] = *(const bf16x8*)&As[curA + ((wv >> 1)*4 + mi)*512 + lane*8];
        #pragma unroll
        for (int ni = 0; ni < NI; ++ni)
            bfr[ni] = *(const bf16x8*)&Bs[curB + ((wv & 1)*NI + ni)*512 + lane*8];

        #pragma unroll
        for (int mi = 0; mi < 4; ++mi)
            #pragma unroll
            for (int ni = 0; ni < NI; ++ni) {
                if (MODE == 1)   // swapped: d on quad axis, t on l16
                    acc[mi][ni] = __builtin_amdgcn_mfma_f32_16x16x32_bf16(
                        bfr[ni], af[mi], acc[mi][ni], 0, 0, 0);
                else
                    acc[mi][ni] = __builtin_amdgcn_mfma_f32_16x16x32_bf16(
                        af[mi], bfr[ni], acc[mi][ni], 0, 0, 0);
            }
        __builtin_amdgcn_s_barrier();          // all waves done reading buf cur
    }

    // epilogue
    #pragma unroll
    for (int mi = 0; mi < 4; ++mi) {
        #pragma unroll
        for (int ni = 0; ni < NI; ++ni) {
            if (MODE == 0) {
                const int col = n_base + wn + ni*16 + l16;
                const float bv = bias[col & 1023];
                #pragma unroll
                for (int r = 0; r < 4; ++r) {
                    const int row = m_base + wm + mi*16 + quad*4 + r;
                    ((float*)Out)[(size_t)row * NC + col] =
                        (acc[mi][ni][r] + bv) * oscale;
                }
            } else if (MODE == 1) {
                const int d0 = n_base + wn + ni*16 + quad*4;
                const int t  = m_base + wm + mi*16 + l16;
                const float4 b4 = *(const float4*)&bias[d0];
                const int bb = t >> 11, tt = t & (NT - 1);
                const int h  = (d0 >> 6) & (NH - 1), dd0 = d0 & 63;
                const int bh = bb * NH + h;
                const size_t idx0 =
                    ((size_t)((bh*128 + (tt >> 4))*2 + (dd0 >> 5)))*512
                    + (size_t)((((dd0 >> 3) & 3)*16 + (tt & 15))*8 + (dd0 & 7));
                ushort4 st;
                st.x = f2bf((acc[mi][ni][0] + b4.x) * oscale);
                st.y = f2bf((acc[mi][ni][1] + b4.y) * oscale);
                st.z = f2bf((acc[mi][ni][2] + b4.z) * oscale);
                st.w = f2bf((acc[mi][ni][3] + b4.w) * oscale);
                *(ushort4*)&((unsigned short*)Out)[idx0] = st;
            } else {
                const int col = n_base + wn + ni*16 + l16;
                const float bv = bias[col & 1023];
                const int row0 = m_base + wm + mi*16 + quad*4;
                const int bb = row0 >> 11, t0 = row0 & (NT - 1);
                const int h  = (col >> 6) & (NH - 1), hd = col & 63;
                const int bh = bb * NH + h;
                const int tk0 = t0 & 31;
                const int qv  = (tk0 >> 2) & 3;
                const int jv0 = (tk0 >> 4) << 2;      // tk0&3 == 0
                const size_t idx0 =
                    ((size_t)((bh*64 + (t0 >> 5))*4 + (hd >> 4)))*512
                    + (size_t)((qv*16 + (hd & 15))*8 + jv0);
                ushort4 st;
                st.x = f2bf((acc[mi][ni][0] + bv) * oscale);
                st.y = f2bf((acc[mi][ni][1] + bv) * oscale);
                st.z = f2bf((acc[mi][ni][2] + bv) * oscale);
                st.w = f2bf((acc[mi][ni][3] + bv) * oscale);
                *(ushort4*)&((unsigned short*)Out)[idx0] = st;
            }
        }
    }
}

// Fused QKV (split form): grid (64, 24); blockIdx.y: 0-7 Q, 8-15 K, 16-23 V.
// 1536 blocks keep inter-block phase stagger (m114).
#define QSCALE (0.03125f * 1.44269504088896340736f)   // (1/sqrt(C)) * log2(e)

__global__ __launch_bounds__(256) void gemm_qkv(
    const unsigned short* __restrict__ A,
    const unsigned short* __restrict__ Wq, const unsigned short* __restrict__ Wk,
    const unsigned short* __restrict__ Wv,
    const float* __restrict__ bq, const float* __restrict__ bk,
    const float* __restrict__ bv,
    unsigned short* __restrict__ Qo, unsigned short* __restrict__ Ko,
    unsigned short* __restrict__ Vo)
{
    __shared__ __align__(16) unsigned short As[2*TM*BK];
    __shared__ __align__(16) unsigned short Bs[2*128*BK];
    const int wi = blockIdx.y >> 3;
    const int n_base = (blockIdx.y & 7) * 128;
    const int m_base = blockIdx.x * TM;
    if (wi == 0)
        gemm_core<1,128>(A, Wq, bq, Qo, As, Bs, m_base, n_base, QSCALE);
    else if (wi == 1)
        gemm_core<1,128>(A, Wk, bk, Ko, As, Bs, m_base, n_base, 1.0f);
    else
        gemm_core<2,128>(A, Wv, bv, Vo, As, Bs, m_base, n_base, 1.0f);
}

// R10: TN=64 -> grid (64,16) = 1024 blocks = 4/CU (was 512 = 2/CU).
__global__ __launch_bounds__(256) void gemm_out(
    const unsigned short* __restrict__ A,
    const unsigned short* __restrict__ W,
    const float* __restrict__ bias,
    float* __restrict__ Out)
{
    __shared__ __align__(16) unsigned short As[2*TM*BK];
    __shared__ __align__(16) unsigned short Bs[2*64*BK];
    gemm_core<0,64>(A, W, bias, Out, As, Bs, blockIdx.x * TM, blockIdx.y * 64, 1.0f);
}

// ---------------- flash attention (causal), transposed-P scheme -------------
// S^T = mfma(A=K, B=Q); C-layout of S^T: l16 = Q-row, quad*4+r = key.
// exp -> P^T; pack pairs (v_perm RTZ) into B-operand of O^T = mfma(V^T, P^T).
// REGISTER K/V loads (no LDS, R8 lesson). T5 setprio (m191). Strip-pair
// fusion (R3). Diag-half skip (R4). lsum tree-reduce (R5).
__device__ __forceinline__ void attn_tile(
    const bf16x8 kf[4][2], const bf16x8 vf[4][2],
    const bf16x8 q[4], floatx4 o[2][4], float l[2],
    bool diag, bool skiphi, int q0, int j0, int quad, int l16)
{
    #pragma unroll
    for (int sub = 0; sub < 2; ++sub) {
        const bf16x8 qx0 = q[sub*2];
        const bf16x8 qx1 = q[sub*2 + 1];

        floatx4 s[4];
        __builtin_amdgcn_s_setprio(1);
        #pragma unroll
        for (int ct = 0; ct < 2; ++ct) {
            s[ct] = (floatx4){0.f,0.f,0.f,0.f};
            s[ct] = __builtin_amdgcn_mfma_f32_16x16x32_bf16(kf[ct][0], qx0, s[ct], 0,0,0);
            s[ct] = __builtin_amdgcn_mfma_f32_16x16x32_bf16(kf[ct][1], qx1, s[ct], 0,0,0);
        }
        if (!skiphi) {
            #pragma unroll
            for (int ct = 2; ct < 4; ++ct) {
                s[ct] = (floatx4){0.f,0.f,0.f,0.f};
                s[ct] = __builtin_amdgcn_mfma_f32_16x16x32_bf16(kf[ct][0], qx0, s[ct], 0,0,0);
                s[ct] = __builtin_amdgcn_mfma_f32_16x16x32_bf16(kf[ct][1], qx1, s[ct], 0,0,0);
            }
        }
        __builtin_amdgcn_s_setprio(0);

        float p[4][4];
        float psum[4];
        const int row = q0 + sub*16 + l16;
        #pragma unroll
        for (int ct = 0; ct < 2; ++ct) {
            if (!diag) {
                #pragma unroll
                for (int r = 0; r < 4; ++r)
                    p[ct][r] = __builtin_amdgcn_exp2f(s[ct][r]);
            } else {
                #pragma unroll
                for (int r = 0; r < 4; ++r) {
                    const int key = j0 + ct*16 + quad*4 + r;
                    p[ct][r] = (key <= row) ? __builtin_amdgcn_exp2f(s[ct][r]) : 0.f;
                }
            }
            psum[ct] = (p[ct][0] + p[ct][1]) + (p[ct][2] + p[ct][3]);
        }
        if (!skiphi) {
            #pragma unroll
            for (int ct = 2; ct < 4; ++ct) {
                if (!diag) {
                    #pragma unroll
                    for (int r = 0; r < 4; ++r)
                        p[ct][r] = __builtin_amdgcn_exp2f(s[ct][r]);
                } else {
                    #pragma unroll
                    for (int r = 0; r < 4; ++r) {
                        const int key = j0 + ct*16 + quad*4 + r;
                        p[ct][r] = (key <= row) ? __builtin_amdgcn_exp2f(s[ct][r]) : 0.f;
                    }
                }
                psum[ct] = (p[ct][0] + p[ct][1]) + (p[ct][2] + p[ct][3]);
            }
            l[sub] += (psum[0] + psum[1]) + (psum[2] + psum[3]);
        } else {
            l[sub] += psum[0] + psum[1];
        }

        union { bf16x8 v; unsigned int u[4]; } pf0;
        pf0.u[0] = pk2(p[0][0], p[0][1]); pf0.u[1] = pk2(p[0][2], p[0][3]);
        pf0.u[2] = pk2(p[1][0], p[1][1]); pf0.u[3] = pk2(p[1][2], p[1][3]);

        __builtin_amdgcn_s_setprio(1);
        #pragma unroll
        for (int nt = 0; nt < 4; ++nt)
            o[sub][nt] = __builtin_amdgcn_mfma_f32_16x16x32_bf16(vf[nt][0], pf0.v, o[sub][nt], 0,0,0);
        __builtin_amdgcn_s_setprio(0);

        if (!skiphi) {
            union { bf16x8 v; unsigned int u[4]; } pf1;
            pf1.u[0] = pk2(p[2][0], p[2][1]); pf1.u[1] = pk2(p[2][2], p[2][3]);
            pf1.u[2] = pk2(p[3][0], p[3][1]); pf1.u[3] = pk2(p[3][2], p[3][3]);
            __builtin_amdgcn_s_setprio(1);
            #pragma unroll
            for (int nt = 0; nt < 4; ++nt)
                o[sub][nt] = __builtin_amdgcn_mfma_f32_16x16x32_bf16(vf[nt][1], pf1.v, o[sub][nt], 0,0,0);
            __builtin_amdgcn_s_setprio(0);
        }
    }
}

__device__ __forceinline__ void attn_store(
    unsigned short* __restrict__ Y, const floatx4 o[2][4], const float l[2],
    int q0, int b, int h, int quad, int l16)
{
    float la = l[0], lb = l[1];
    la += __shfl_xor(la, 16); la += __shfl_xor(la, 32);
    lb += __shfl_xor(lb, 16); lb += __shfl_xor(lb, 32);
    const float ia = 1.0f / la, ib = 1.0f / lb;
    const size_t Rbase = (size_t)((b*NT + q0) >> 4);
    const int cg = (quad >> 1), co = (quad & 1)*4;
    #pragma unroll
    for (int nt = 0; nt < 4; ++nt) {
        const size_t base = ((Rbase*32 + h*2 + (nt >> 1))*512)
                          + (size_t)((((nt & 1)*2 + cg)*16 + l16)*8 + co);
        ushort4 wa, wb;
        wa.x = f2bf(o[0][nt][0]*ia); wa.y = f2bf(o[0][nt][1]*ia);
        wa.z = f2bf(o[0][nt][2]*ia); wa.w = f2bf(o[0][nt][3]*ia);
        wb.x = f2bf(o[1][nt][0]*ib); wb.y = f2bf(o[1][nt][1]*ib);
        wb.z = f2bf(o[1][nt][2]*ib); wb.w = f2bf(o[1][nt][3]*ib);
        *(ushort4*)&Y[base]         = wa;
        *(ushort4*)&Y[base + 16384] = wb;   // +1 row-tile (32*512)
    }
}

__device__ __forceinline__ void attn_pair(
    const unsigned short* __restrict__ Qf,
    const unsigned short* __restrict__ Kf,
    const unsigned short* __restrict__ Vf,
    unsigned short* __restrict__ Y,
    int bh, int stA, int stB, int lane)
{
    const int quad = lane >> 4, l16 = lane & 15;
    const int b = bh >> 4, h = bh & (NH - 1);
    const int q0A = stA * 32, q0B = stB * 32;
    const int FA = q0A >> 6, FB = q0B >> 6;    // FA < FB always (stA<32<=stB)
    const bool skA = (q0A & 32) == 0;          // even strip: diag upper half dead
    const bool skB = (q0B & 32) == 0;

    const size_t qbA = ((size_t)(bh*128 + stA*2))*1024 + (size_t)lane*8;
    const size_t qbB = ((size_t)(bh*128 + stB*2))*1024 + (size_t)lane*8;
    bf16x8 qA[4], qB[4];
    qA[0] = *(const bf16x8*)&Qf[qbA];
    qA[1] = *(const bf16x8*)&Qf[qbA + 512];
    qA[2] = *(const bf16x8*)&Qf[qbA + 1024];
    qA[3] = *(const bf16x8*)&Qf[qbA + 1536];
    qB[0] = *(const bf16x8*)&Qf[qbB];
    qB[1] = *(const bf16x8*)&Qf[qbB + 512];
    qB[2] = *(const bf16x8*)&Qf[qbB + 1024];
    qB[3] = *(const bf16x8*)&Qf[qbB + 1536];

    const unsigned short* kp = Kf + (size_t)bh*131072 + (size_t)lane*8;
    const unsigned short* vp = Vf + (size_t)bh*131072 + (size_t)lane*8;

    floatx4 oA[2][4], oB[2][4];
    float lA[2] = {0.f, 0.f}, lB[2] = {0.f, 0.f};
    #pragma unroll
    for (int s2 = 0; s2 < 2; ++s2)
        #pragma unroll
        for (int nt = 0; nt < 4; ++nt) {
            oA[s2][nt] = (floatx4){0.f,0.f,0.f,0.f};
            oB[s2][nt] = (floatx4){0.f,0.f,0.f,0.f};
        }

    for (int f = 0; f <= FB; ++f) {
        const int j0 = f * 64;
        bf16x8 kf[4][2], vf[4][2];
        const unsigned short* kt = kp + (size_t)f * 4096;
        #pragma unroll
        for (int ct = 0; ct < 4; ++ct) {
            kf[ct][0] = *(const bf16x8*)&kt[ct*1024];
            kf[ct][1] = *(const bf16x8*)&kt[ct*1024 + 512];
        }
        const unsigned short* vt = vp + (size_t)f * 4096;
        #pragma unroll
        for (int nt = 0; nt < 4; ++nt) {
            vf[nt][0] = *(const bf16x8*)&vt[nt*512];
            vf[nt][1] = *(const bf16x8*)&vt[2048 + nt*512];
        }

        if (f <= FA)
            attn_tile(kf, vf, qA, oA, lA, f == FA, (f == FA) && skA,
                      q0A, j0, quad, l16);
        attn_tile(kf, vf, qB, oB, lB, f == FB, (f == FB) && skB,
                  q0B, j0, quad, l16);
    }

    attn_store(Y, oA, lA, q0A, b, h, quad, l16);
    attn_store(Y, oB, lB, q0B, b, h, quad, l16);
}

// T1 XCD-grouping: 512 blocks, 1-D. bh depends only on L mod 64 so all 8
// blocks of one (b,h) share L%8 (= XCD): each XCD serves 8 heads' K/V (4MB)
// from its own L2.
// R10 length-balance: block f-loop length = FBmax(x) = 31-2x. With exactly
// 2 resident blocks/CU and linear dispatch, CU c hosts L=c and L=c+256,
// i.e. g and g+4 (g = L>>6). Mapping x = g<4 ? g : 11-g pairs x with 7-x
// on each CU -> per-CU length sum uniform (48) instead of 54..42 skew.
// Bijective over g=0..7; bh decode (L%64) untouched, so T1 is preserved.
__global__ __launch_bounds__(256, 2) void flash_attn(
    const unsigned short* __restrict__ Qf,
    const unsigned short* __restrict__ Kf,
    const unsigned short* __restrict__ Vf,
    unsigned short* __restrict__ Y)
{
    const int tid  = threadIdx.x;
    const int wave = tid >> 6;
    const int lane = tid & 63;
    const int L  = blockIdx.x;
    const int bh = (L & 7) * 8 + ((L >> 3) & 7);
    const int g  = L >> 6;
    const int x  = (g < 4) ? g : 11 - g;
    const int w  = x * 4 + wave;   // 0..31
    attn_pair(Qf, Kf, Vf, Y, bh, w, 63 - w, lane);
}

// ---------------- launch ----------------
extern "C" void kernel_launch(void* const* d_in, const int* in_sizes, int n_in,
                              void* d_out, int out_size, void* d_ws, size_t ws_size,
                              hipStream_t stream) {
    const float* x  = (const float*)d_in[0];
    const float* Wq = (const float*)d_in[1];
    const float* bq = (const float*)d_in[2];
    const float* Wk = (const float*)d_in[3];
    const float* bk = (const float*)d_in[4];
    const float* Wv = (const float*)d_in[5];
    const float* bv = (const float*)d_in[6];
    const float* Wo = (const float*)d_in[7];
    const float* bo = (const float*)d_in[8];

    char* ws = (char*)d_ws;
    size_t off = 0;
    auto alloc = [&](size_t bytes) -> void* {
        void* p = ws + off;
        off += (bytes + 255) & ~(size_t)255;
        return p;
    };
    unsigned short* xb  = (unsigned short*)alloc((size_t)NM * NC * 2);
    unsigned short* Wqb = (unsigned short*)alloc((size_t)NC * NC * 2);
    unsigned short* Wkb = (unsigned short*)alloc((size_t)NC * NC * 2);
    unsigned short* Wvb = (unsigned short*)alloc((size_t)NC * NC * 2);
    unsigned short* Wob = (unsigned short*)alloc((size_t)NC * NC * 2);
    unsigned short* Qb  = (unsigned short*)alloc((size_t)NM * NC * 2);
    unsigned short* Kb  = (unsigned short*)alloc((size_t)NM * NC * 2);
    unsigned short* Vtb = (unsigned short*)alloc((size_t)NM * NC * 2);
    unsigned short* Yb  = (unsigned short*)alloc((size_t)NM * NC * 2);

    // 16384 x-tiles + 4*2048 weight tiles = 24576 wave-tiles
    cast_all<<<(24576*64)/256, 256, 0, stream>>>(
        x, Wq, Wk, Wv, Wo, xb, Wqb, Wkb, Wvb, Wob);

    gemm_qkv<<<dim3(NM / TM, 24), 256, 0, stream>>>(
        xb, Wqb, Wkb, Wvb, bq, bk, bv, Qb, Kb, Vtb);

    flash_attn<<<dim3(512), 256, 0, stream>>>(Qb, Kb, Vtb, Yb);

    gemm_out<<<dim3(NM / TM, NC / 64), 256, 0, stream>>>(Yb, Wob, bo, (float*)d_out);
}